// Round 4
// baseline (462.440 us; speedup 1.0000x reference)
//
#include <hip/hip_runtime.h>
#include <math.h>

#define S 4
#define G 3
#define NN 20000
#define EE 320000
#define D 64
#define SG (S*G)

#define RGS 32           // dst-ranges per graph
#define RNODES2 625      // NN / RGS
#define BCAP 14336       // bucket capacity per (sg,range); mean 10000 + pad(<=3/node)
#define CHUNKA 100       // edge chunks per sg in binA; 320000/100 = 3200 edges/block

// layer tasks: 12 sg x 313 tiles (block = 64 consecutive sorted ranks, 4 waves x 16)
#define LTILES 313
#define LTASKS (12*LTILES)   // 3756
#define LQ (LTASKS/8)        // 469
#define LR (LTASKS%8)        // 4
#define NGRP   (NN/16)       // 1250 sorted 16-row groups per sg

static __device__ __forceinline__ float rcpf(float x){ return __builtin_amdgcn_rcpf(x); }
static __device__ __forceinline__ float sigmf(float x){ return rcpf(1.0f + __expf(-x)); }
// fast tanh: 1 - 2/(e^{2x}+1), v_rcp for the divide; saturates correctly
static __device__ __forceinline__ float tanhf_fast(float x){
    float t = __expf(2.0f*x);
    return 1.0f - 2.0f*rcpf(t + 1.0f);
}

// float -> bf16 bits, round-nearest-even
static __device__ __forceinline__ unsigned short f2bf(float f){
    union { float f; unsigned u; } v; v.f = f;
    unsigned r = v.u + 0x7FFF + ((v.u >> 16) & 1);
    return (unsigned short)(r >> 16);
}

typedef short bf16x8 __attribute__((ext_vector_type(8)));
typedef float f32x4  __attribute__((ext_vector_type(4)));

// ---------------- Phase A: bin edges into 32 dst-range buckets, packed (dstLoc<<15)|src ----------------

__global__ __launch_bounds__(256) void binA_kernel(const int* __restrict__ ei,
                                                   int* __restrict__ bcur,
                                                   int* __restrict__ bkt){
    __shared__ int wcnt[4*RGS];
    __shared__ int wb[4*RGS];
    int chunk = blockIdx.x, sg = blockIdx.y;
    int tid = threadIdx.x, w = tid >> 6;
    const int* srcp = ei + (size_t)(sg*2 + 0)*EE;
    const int* dstp = ei + (size_t)(sg*2 + 1)*EE;
    const int EPC = EE/CHUNKA;               // 3200
    int start = chunk*EPC, end = start + EPC;

    for (int it = 0; it < (EPC + 1023)/1024; ++it){
        if (tid < 4*RGS) wcnt[tid] = 0;
        __syncthreads();
        int e = start + it*1024 + tid*4;
        bool valid = e < end;
        int d_[4], s_[4], r_[4], dl_[4], rk_[4];
        if (valid){
            int4 d4 = *(const int4*)&dstp[e];
            int4 s4 = *(const int4*)&srcp[e];
            d_[0]=d4.x; d_[1]=d4.y; d_[2]=d4.z; d_[3]=d4.w;
            s_[0]=s4.x; s_[1]=s4.y; s_[2]=s4.z; s_[3]=s4.w;
            #pragma unroll
            for (int j = 0; j < 4; ++j){
                int r = d_[j] / RNODES2;
                r_[j]  = r;
                dl_[j] = d_[j] - r*RNODES2;
                rk_[j] = atomicAdd(&wcnt[w*RGS + r], 1);
            }
        }
        __syncthreads();
        if (tid < RGS){
            int c0 = wcnt[0*RGS+tid], c1 = wcnt[1*RGS+tid];
            int c2 = wcnt[2*RGS+tid], c3 = wcnt[3*RGS+tid];
            int tot = c0+c1+c2+c3;
            int gb = 0;
            if (tot > 0) gb = atomicAdd(&bcur[sg*RGS + tid], tot);
            wb[0*RGS+tid] = gb;
            wb[1*RGS+tid] = gb + c0;
            wb[2*RGS+tid] = gb + c0 + c1;
            wb[3*RGS+tid] = gb + c0 + c1 + c2;
        }
        __syncthreads();
        if (valid){
            #pragma unroll
            for (int j = 0; j < 4; ++j){
                int pos = wb[w*RGS + r_[j]] + rk_[j];
                if (pos < BCAP)
                    bkt[(size_t)(sg*RGS + r_[j])*BCAP + pos] = (dl_[j] << 15) | s_[j];
            }
        }
    }
}

// ---------------- Phase B: per (sg,range): hist -> padded scan -> degree-sort -> CSR segment ----------------
// Segments padded to x4 (aligned int4 index reads). Nodes within each range are
// counting-sorted by degree ascending; off2/deg2/nid2 are in sorted order so a
// wave's 16 consecutive slots have near-equal degree -> minimal padding waste.

__global__ __launch_bounds__(256) void buildB_kernel(int* __restrict__ bkt,
                                                     const int* __restrict__ bcur,
                                                     int* __restrict__ off2,
                                                     int* __restrict__ deg2,
                                                     int* __restrict__ nid2,
                                                     int* __restrict__ offU){
    __shared__ int hist[RNODES2];      // degree per node
    __shared__ int pref[RNODES2];      // CSR scatter cursor
    __shared__ int seg[BCAP];          // 57.3 KB
    __shared__ int sums[256];
    __shared__ int dh[64];             // degree histogram / sort cursor
    int sg = blockIdx.x / RGS, rg = blockIdx.x % RGS;
    int tid = threadIdx.x;
    int cnt = bcur[sg*RGS + rg];
    if (cnt > BCAP) cnt = BCAP;
    size_t base = (size_t)(sg*RGS + rg)*BCAP;
    int gnode = sg*NN + rg*RNODES2;

    for (int i = tid; i < RNODES2; i += 256) hist[i] = 0;
    if (tid < 64) dh[tid] = 0;
    __syncthreads();
    for (int j = tid; j < cnt; j += 256)
        atomicAdd(&hist[bkt[base + j] >> 15], 1);
    __syncthreads();

    int lo = tid*3, hi = min(lo+3, RNODES2);
    int s = 0;
    for (int i = lo; i < hi; ++i) s += (hist[i] + 3) & ~3;   // padded sizes
    sums[tid] = s; __syncthreads();
    for (int ofs = 1; ofs < 256; ofs <<= 1){
        int v = (tid >= ofs) ? sums[tid-ofs] : 0;
        __syncthreads();
        sums[tid] += v;
        __syncthreads();
    }
    int run = sums[tid] - s;
    for (int i = lo; i < hi; ++i){
        pref[i] = run;                       // CSR cursor (mutated below)
        offU[gnode + i] = (int)base + run;   // unsorted offset (read back in sort)
        run += (hist[i] + 3) & ~3;
    }
    __syncthreads();

    // degree histogram -> prefix -> sorted scatter of (off,deg,nid)
    for (int i = tid; i < RNODES2; i += 256)
        atomicAdd(&dh[min(hist[i], 63)], 1);
    __syncthreads();
    if (tid == 0){
        int r = 0;
        for (int k = 0; k < 64; ++k){ int c = dh[k]; dh[k] = r; r += c; }
    }
    __syncthreads();
    for (int i = tid; i < RNODES2; i += 256){
        int pos = atomicAdd(&dh[min(hist[i], 63)], 1);
        off2[gnode + pos] = offU[gnode + i];
        deg2[gnode + pos] = hist[i];
        nid2[gnode + pos] = rg*RNODES2 + i;
    }
    __syncthreads();

    for (int j = tid; j < cnt; j += 256){
        int p = bkt[base + j];
        int slot = atomicAdd(&pref[p >> 15], 1);
        if (slot < BCAP) seg[slot] = p & 0x7FFF;
    }
    __syncthreads();

    int padtot = min(sums[255], BCAP);
    for (int j = tid; j < padtot; j += 256) bkt[base + j] = seg[j];
}

// ---------------- x -> bf16 convert ----------------

__global__ __launch_bounds__(256) void convert_kernel(const float* __restrict__ x,
                                                      unsigned short* __restrict__ xb){
    int idx = blockIdx.x*256 + threadIdx.x;
    if (idx >= SG*NN*16) return;
    float4 v = ((const float4*)x)[idx];
    uint2 pk;
    pk.x = (unsigned)f2bf(v.x) | ((unsigned)f2bf(v.y) << 16);
    pk.y = (unsigned)f2bf(v.z) | ((unsigned)f2bf(v.w) << 16);
    ((uint2*)xb)[idx] = pk;
}

// ---------------- weight prep: all bf16, [col][k] layouts ----------------

__global__ __launch_bounds__(256) void wprep2_kernel(const float* __restrict__ W1l,
                                                     const float* __restrict__ W1r,
                                                     const float* __restrict__ W2l,
                                                     const float* __restrict__ W2r,
                                                     const float* __restrict__ Wih,
                                                     const float* __restrict__ Whh,
                                                     const float* __restrict__ bih,
                                                     const float* __restrict__ bhh,
                                                     unsigned short* __restrict__ WL1,
                                                     unsigned short* __restrict__ WL2,
                                                     unsigned short* __restrict__ Wt,
                                                     float* __restrict__ bc){
    int idx = blockIdx.x*256 + threadIdx.x;
    if (idx < 24576){
        int g = idx >> 13, rem = idx & 8191, col = rem >> 7, k = rem & 127;
        float v = (k < 64) ? W1l[((size_t)g*64 + k)*64 + col]
                           : W1r[((size_t)g*64 + (k-64))*64 + col];
        WL1[idx] = f2bf(v);
    } else if (idx < 49152){
        int t = idx - 24576;
        int g = t >> 13, rem = t & 8191, col = rem >> 7, k = rem & 127;
        float v = (k < 64) ? W2l[((size_t)g*64 + k)*64 + col]
                           : W2r[((size_t)g*64 + (k-64))*64 + col];
        WL2[t] = f2bf(v);
    } else if (idx < 81920){
        int t = idx - 49152;
        int col = t >> 7, k = t & 127;
        float v = (k < 64) ? Wih[col*64 + k] : Whh[col*64 + (k - 64)];
        Wt[t] = f2bf(v);
    } else if (idx < 82176){
        int t = idx - 81920;
        bc[t] = bih[t] + bhh[t];
    }
}

// ---------------- SAGE layer: MFMA aggregation, degree-sorted rows.
// Block = 64 CONSECUTIVE sorted ranks (wave w -> group tile*4+w) so all 4 waves
// of a block run near-equal time (block-granularity residency: a straggler wave
// holds the whole block's slots -> round-3's 28% occupancy). High-degree tiles
// launch first so long blocks pack at the start, not the tail. ----------------

#define WP 72

#define LOADCH(F, IX, JB) { \
    int ii0_ = (IX).x, ii1_ = (IX).y, ii2_ = (IX).z, ii3_ = (IX).w; \
    unsigned o0_ = (((unsigned)ii0_) << 7) + qb; if ((JB) + 0 >= dg) o0_ = zoff; \
    unsigned o1_ = (((unsigned)ii1_) << 7) + qb; if ((JB) + 1 >= dg) o1_ = zoff; \
    unsigned o2_ = (((unsigned)ii2_) << 7) + qb; if ((JB) + 2 >= dg) o2_ = zoff; \
    unsigned o3_ = (((unsigned)ii3_) << 7) + qb; if ((JB) + 3 >= dg) o3_ = zoff; \
    F[0] = *(const bf16x8*)(inbc + o0_); F[1] = *(const bf16x8*)(inbc + o0_ + 64); \
    F[2] = *(const bf16x8*)(inbc + o1_); F[3] = *(const bf16x8*)(inbc + o1_ + 64); \
    F[4] = *(const bf16x8*)(inbc + o2_); F[5] = *(const bf16x8*)(inbc + o2_ + 64); \
    F[6] = *(const bf16x8*)(inbc + o3_); F[7] = *(const bf16x8*)(inbc + o3_ + 64); \
}

#define MFMAS(F) { \
    __builtin_amdgcn_s_setprio(1); \
    _Pragma("unroll") \
    for (int j_ = 0; j_ < 4; ++j_){ \
        _Pragma("unroll") \
        for (int ct_ = 0; ct_ < 4; ++ct_) \
            acc[ct_] = __builtin_amdgcn_mfma_f32_16x16x32_bf16(F[2*j_],   B0[ct_], acc[ct_], 0, 0, 0); \
        _Pragma("unroll") \
        for (int ct_ = 0; ct_ < 4; ++ct_) \
            acc[ct_] = __builtin_amdgcn_mfma_f32_16x16x32_bf16(F[2*j_+1], B1[ct_], acc[ct_], 0, 0, 0); \
    } \
    __builtin_amdgcn_s_setprio(0); \
}

__global__ __launch_bounds__(256,3) void layer_kernel(const unsigned short* __restrict__ xb,
                                                    const int* __restrict__ off2,
                                                    const int* __restrict__ deg2,
                                                    const int* __restrict__ nid2,
                                                    const int* __restrict__ csr,
                                                    const unsigned short* __restrict__ WL,
                                                    const float* __restrict__ bias,
                                                    unsigned short* __restrict__ outb){
    __shared__ unsigned short sO[4][16*WP];  // out transpose staging (same-wave, no barrier)
    int L = blockIdx.x;
    // bijective XCD swizzle for LTASKS = 3756 (m204 form): L%8 -> contiguous task chunk
    int xcd = L & 7;
    int task = ((xcd < LR) ? xcd*(LQ+1) : LR*(LQ+1) + (xcd-LR)*LQ) + (L >> 3);
    int sg = task / LTILES;
    int tsel = task - sg*LTILES;
    int tile = (LTILES-1) - tsel;           // high-degree (long) blocks first
    int g = sg % G;
    int tid = threadIdx.x;
    int wave = tid >> 6, lane = tid & 63;
    int r = lane & 15, q = lane >> 4;
    unsigned qb = (unsigned)(q << 4);       // byte offset of this lane's 8-ch slice
    const char* inbc = (const char*)(xb + (size_t)sg*NN*D);

    // block = 64 consecutive sorted ranks; wave w owns group tile*4+w (16 ranks)
    int gid = tile*4 + wave;
    bool wv = (gid < NGRP);

    // B fragments (Wl part, kc=0,1)
    const unsigned short* WLg = WL + (size_t)g*64*128;
    bf16x8 B0[4], B1[4];
    #pragma unroll
    for (int ct = 0; ct < 4; ++ct){
        B0[ct] = *(const bf16x8*)&WLg[(ct*16 + r)*128 + 0*32 + q*8];
        B1[ct] = *(const bf16x8*)&WLg[(ct*16 + r)*128 + 1*32 + q*8];
    }
    asm volatile("" : "+v"(B0[0]), "+v"(B0[1]), "+v"(B0[2]), "+v"(B0[3]),
                      "+v"(B1[0]), "+v"(B1[1]), "+v"(B1[2]), "+v"(B1[3]));

    int idx = sg*NN + gid*16 + r;
    int node = 0, dg = 0, a = 0;
    if (wv){
        node = nid2[idx];
        a    = off2[idx];
        dg   = deg2[idx];
    }
    // wave-uniform loop bound: max degree over the 16 slots (sorted -> near-equal)
    int mx = dg;
    mx = max(mx, __shfl_xor(mx, 1));
    mx = max(mx, __shfl_xor(mx, 2));
    mx = max(mx, __shfl_xor(mx, 4));
    mx = max(mx, __shfl_xor(mx, 8));

    // self-row loads issued early; consumed after the neighbor loop
    bf16x8 S0 = *(const bf16x8*)(inbc + (((unsigned)node) << 7) + qb);
    bf16x8 S1 = *(const bf16x8*)(inbc + (((unsigned)node) << 7) + qb + 64);

    // shared zero row lives at absolute row SG*NN -> relative (SG-sg)*NN
    unsigned zoff = (((unsigned)((SG - sg)*NN)) << 7) + qb;

    f32x4 acc[4];
    #pragma unroll
    for (int ct = 0; ct < 4; ++ct) acc[ct] = (f32x4){0.f,0.f,0.f,0.f};

    if (mx > 0){
        // 2 chunks of fragments + 2 index vectors in flight (depth-2 attempt;
        // TLP from equal-time waves is the primary latency cover)
        int4 ix0 = *(const int4*)&csr[a];
        int4 ix1 = *(const int4*)&csr[a + 4];
        bf16x8 FA[8], FB[8];
        LOADCH(FA, ix0, 0);
        LOADCH(FB, ix1, 4);
        ix0 = *(const int4*)&csr[a + 8];
        ix1 = *(const int4*)&csr[a + 12];
        int nch = (mx + 3) >> 2;
        for (int c = 0; c < nch; c += 2){
            MFMAS(FA);
            LOADCH(FA, ix0, (c + 2)*4);
            ix0 = *(const int4*)&csr[a + (c + 4)*4];
            if (c + 1 < nch){
                MFMAS(FB);
                LOADCH(FB, ix1, (c + 3)*4);
                ix1 = *(const int4*)&csr[a + (c + 5)*4];
            }
        }
    }

    // scale neighbor sum by 1/deg (acc reg 'reg' holds slot-row q*4+reg)
    float inv[4];
    #pragma unroll
    for (int reg = 0; reg < 4; ++reg){
        int d = __shfl(dg, (q << 2) | reg, 16);
        inv[reg] = (d > 0) ? rcpf((float)d) : 0.0f;
    }
    #pragma unroll
    for (int ct = 0; ct < 4; ++ct)
        #pragma unroll
        for (int reg = 0; reg < 4; ++reg)
            acc[ct][reg] *= inv[reg];

    // self term x_i @ Wr (kc=2,3 of WL)
    #pragma unroll
    for (int ct = 0; ct < 4; ++ct){
        bf16x8 b2 = *(const bf16x8*)&WLg[(ct*16 + r)*128 + 2*32 + q*8];
        acc[ct] = __builtin_amdgcn_mfma_f32_16x16x32_bf16(S0, b2, acc[ct], 0, 0, 0);
        bf16x8 b3 = *(const bf16x8*)&WLg[(ct*16 + r)*128 + 3*32 + q*8];
        acc[ct] = __builtin_amdgcn_mfma_f32_16x16x32_bf16(S1, b3, acc[ct], 0, 0, 0);
    }

    // epilogue: bias + tanh -> bf16, transpose through LDS (same wave), scatter store by nid
    #pragma unroll
    for (int ct = 0; ct < 4; ++ct){
        float bv = bias[g*64 + ct*16 + r];
        #pragma unroll
        for (int reg = 0; reg < 4; ++reg)
            sO[wave][(q*4+reg)*WP + ct*16 + r] = f2bf(tanhf_fast(acc[ct][reg] + bv));
    }
    if (wv){
        #pragma unroll
        for (int pass = 0; pass < 2; ++pass){
            int rloc = pass*8 + (lane >> 3), chunk = lane & 7;
            int i2 = gid*16 + rloc;
            int nd = nid2[sg*NN + i2];
            uint4 v = *(const uint4*)&sO[wave][rloc*WP + chunk*8];
            *(uint4*)&outb[((size_t)sg*NN + nd)*D + chunk*8] = v;
        }
    }
}

// ---------------- LSTM: col-partitioned waves; Wt read once per block; 3 barriers ----------------

__global__ __launch_bounds__(256) void lstm_kernel(const unsigned short* __restrict__ h2b,
                                                   const unsigned short* __restrict__ Wt,
                                                   const float* __restrict__ bc,
                                                   float* __restrict__ out){
    __shared__ unsigned short sH[64*WP];  // 9.2 KB, whole block's h
    int tid = threadIdx.x;
    int b0 = blockIdx.x * 64;
    int wave = tid >> 6, lane = tid & 63;
    int n0 = lane & 15, q = lane >> 4;
    int jcol = wave*16 + n0;              // output col j in [0,64)

    float bb[4];
    #pragma unroll
    for (int T = 0; T < 4; ++T) bb[T] = bc[T*64 + jcol];

    float c[4][4];  // [rt][reg]
    #pragma unroll
    for (int rt = 0; rt < 4; ++rt)
        #pragma unroll
        for (int reg = 0; reg < 4; ++reg) c[rt][reg] = 0.0f;

    int s_[4], n_[4];
    #pragma unroll
    for (int rt = 0; rt < 4; ++rt){
        int b = b0 + rt*16 + n0;
        s_[rt] = b / NN; n_[rt] = b - s_[rt]*NN;
    }

    #pragma unroll
    for (int t = 0; t < G; ++t){
        f32x4 accv[4][4];  // [rt][T]
        #pragma unroll
        for (int rt = 0; rt < 4; ++rt)
            #pragma unroll
            for (int T = 0; T < 4; ++T) accv[rt][T] = (f32x4){0.f,0.f,0.f,0.f};

        int nkc = (t == 0) ? 2 : 4;
        #pragma unroll
        for (int kc = 0; kc < 4; ++kc){
            if (kc >= nkc) break;
            bf16x8 af[4];
            #pragma unroll
            for (int rt = 0; rt < 4; ++rt){
                if (kc < 2) af[rt] = *(const bf16x8*)&h2b[((size_t)(s_[rt]*G + t)*NN + n_[rt])*D + kc*32 + q*8];
                else        af[rt] = *(const bf16x8*)&sH[(rt*16 + n0)*WP + (kc-2)*32 + q*8];
            }
            #pragma unroll
            for (int T = 0; T < 4; ++T){
                int ct = T*4 + wave;
                bf16x8 bfr = *(const bf16x8*)&Wt[(ct*16 + n0)*128 + kc*32 + q*8];
                #pragma unroll
                for (int rt = 0; rt < 4; ++rt)
                    accv[rt][T] = __builtin_amdgcn_mfma_f32_16x16x32_bf16(af[rt], bfr, accv[rt][T], 0, 0, 0);
            }
        }
        if (t > 0) __syncthreads();   // WAR: all sH reads done before overwrite

        #pragma unroll
        for (int rt = 0; rt < 4; ++rt){
            #pragma unroll
            for (int reg = 0; reg < 4; ++reg){
                float ig = sigmf(accv[rt][0][reg] + bb[0]);
                float fg = sigmf(accv[rt][1][reg] + bb[1]);
                float gg = tanhf_fast(accv[rt][2][reg] + bb[2]);
                float og = sigmf(accv[rt][3][reg] + bb[3]);
                float cn = fg*c[rt][reg] + ig*gg;
                c[rt][reg] = cn;
                float hv = og * tanhf_fast(cn);
                int row = rt*16 + q*4 + reg;
                if (t < G-1) sH[row*WP + jcol] = f2bf(hv);
                else         out[(size_t)(b0 + row)*D + jcol] = hv;
            }
        }
        if (t < G-1) __syncthreads(); // RAW: h visible before next t's reads
    }
}

// ---------------- host ----------------

extern "C" void kernel_launch(void* const* d_in, const int* in_sizes, int n_in,
                              void* d_out, int out_size, void* d_ws, size_t ws_size,
                              hipStream_t stream) {
    const float* x   = (const float*)d_in[0];
    const int*   ei  = (const int*)  d_in[1];
    const float* W1l = (const float*)d_in[2];
    const float* W1r = (const float*)d_in[3];
    const float* b1  = (const float*)d_in[4];
    const float* W2l = (const float*)d_in[5];
    const float* W2r = (const float*)d_in[6];
    const float* b2  = (const float*)d_in[7];
    const float* Wih = (const float*)d_in[8];
    const float* Whh = (const float*)d_in[9];
    const float* bih = (const float*)d_in[10];
    const float* bhh = (const float*)d_in[11];
    float* out = (float*)d_out;

    char* ws = (char*)d_ws;
    size_t cur = 0;
    auto alloc = [&](size_t bytes)->void*{
        cur = (cur + 255) & ~(size_t)255;
        void* p = ws + cur; cur += bytes; return p;
    };
    int*   bkt  = (int*)alloc((size_t)SG*RGS*BCAP*4);   // buckets, then CSR in place
    int*   bcur = (int*)alloc((size_t)SG*RGS*4);
    int*   off2 = (int*)alloc((size_t)SG*NN*4);
    int*   deg2 = (int*)alloc((size_t)SG*NN*4);
    int*   nid2 = (int*)alloc((size_t)SG*NN*4);
    int*   offU = (int*)alloc((size_t)SG*NN*4);
    unsigned short* xb  = (unsigned short*)alloc(((size_t)SG*NN + 1)*D*2);  // +1 zero row
    unsigned short* h1b = (unsigned short*)alloc(((size_t)SG*NN + 1)*D*2);  // +1 zero row
    unsigned short* h2b = (unsigned short*)alloc((size_t)SG*NN*D*2);
    unsigned short* WL1 = (unsigned short*)alloc((size_t)G*64*128*2);
    unsigned short* WL2 = (unsigned short*)alloc((size_t)G*64*128*2);
    unsigned short* Wt  = (unsigned short*)alloc((size_t)256*128*2);
    float* bc   = (float*)alloc((size_t)256*4);
    (void)ws_size; (void)in_sizes; (void)n_in; (void)out_size;

    (void)hipMemsetAsync(bcur, 0, (size_t)SG*RGS*4, stream);
    (void)hipMemsetAsync(xb  + (size_t)SG*NN*D, 0, (size_t)D*2, stream);  // shared zero row
    (void)hipMemsetAsync(h1b + (size_t)SG*NN*D, 0, (size_t)D*2, stream);  // shared zero row

    convert_kernel<<<(SG*NN*16 + 255)/256, 256, 0, stream>>>(x, xb);
    binA_kernel  <<<dim3(CHUNKA, SG), 256, 0, stream>>>(ei, bcur, bkt);
    buildB_kernel<<<SG*RGS, 256, 0, stream>>>(bkt, bcur, off2, deg2, nid2, offU);
    wprep2_kernel<<<321, 256, 0, stream>>>(W1l, W1r, W2l, W2r, Wih, Whh, bih, bhh,
                                           WL1, WL2, Wt, bc);

    layer_kernel<<<LTASKS, 256, 0, stream>>>(xb,  off2, deg2, nid2, bkt, WL1, b1, h1b);
    layer_kernel<<<LTASKS, 256, 0, stream>>>(h1b, off2, deg2, nid2, bkt, WL2, b2, h2b);

    lstm_kernel <<<(S*NN)/64, 256, 0, stream>>>(h2b, Wt, bc, out);
}

// Round 5
// 450.628 us; speedup vs baseline: 1.0262x; 1.0262x over previous
//
#include <hip/hip_runtime.h>
#include <math.h>

#define S 4
#define G 3
#define NN 20000
#define EE 320000
#define D 64
#define SG (S*G)

#define RGS 32           // dst-ranges per graph
#define RNODES2 625      // NN / RGS
#define BCAP 14336       // bucket capacity per (sg,range); mean 10000 + pad(<=3/node)
#define CHUNKA 100       // edge chunks per sg in binA; 320000/100 = 3200 edges/block

// layer tasks: 12 sg x 313 tiles (block = 64 consecutive sorted ranks, 4 waves x 16)
#define LTILES 313
#define LTASKS (12*LTILES)   // 3756
#define LQ (LTASKS/8)        // 469
#define LR (LTASKS%8)        // 4
#define NGRP   (NN/16)       // 1250 sorted 16-row groups per sg

static __device__ __forceinline__ float rcpf(float x){ return __builtin_amdgcn_rcpf(x); }
static __device__ __forceinline__ float sigmf(float x){ return rcpf(1.0f + __expf(-x)); }
// fast tanh: 1 - 2/(e^{2x}+1), v_rcp for the divide; saturates correctly
static __device__ __forceinline__ float tanhf_fast(float x){
    float t = __expf(2.0f*x);
    return 1.0f - 2.0f*rcpf(t + 1.0f);
}

// float -> bf16 bits, round-nearest-even
static __device__ __forceinline__ unsigned short f2bf(float f){
    union { float f; unsigned u; } v; v.f = f;
    unsigned r = v.u + 0x7FFF + ((v.u >> 16) & 1);
    return (unsigned short)(r >> 16);
}

typedef short bf16x8 __attribute__((ext_vector_type(8)));
typedef float f32x4  __attribute__((ext_vector_type(4)));

// ---------------- Phase A: bin edges into 32 dst-range buckets, packed (dstLoc<<15)|src ----------------

__global__ __launch_bounds__(256) void binA_kernel(const int* __restrict__ ei,
                                                   int* __restrict__ bcur,
                                                   int* __restrict__ bkt){
    __shared__ int wcnt[4*RGS];
    __shared__ int wb[4*RGS];
    int chunk = blockIdx.x, sg = blockIdx.y;
    int tid = threadIdx.x, w = tid >> 6;
    const int* srcp = ei + (size_t)(sg*2 + 0)*EE;
    const int* dstp = ei + (size_t)(sg*2 + 1)*EE;
    const int EPC = EE/CHUNKA;               // 3200
    int start = chunk*EPC, end = start + EPC;

    for (int it = 0; it < (EPC + 1023)/1024; ++it){
        if (tid < 4*RGS) wcnt[tid] = 0;
        __syncthreads();
        int e = start + it*1024 + tid*4;
        bool valid = e < end;
        int d_[4], s_[4], r_[4], dl_[4], rk_[4];
        if (valid){
            int4 d4 = *(const int4*)&dstp[e];
            int4 s4 = *(const int4*)&srcp[e];
            d_[0]=d4.x; d_[1]=d4.y; d_[2]=d4.z; d_[3]=d4.w;
            s_[0]=s4.x; s_[1]=s4.y; s_[2]=s4.z; s_[3]=s4.w;
            #pragma unroll
            for (int j = 0; j < 4; ++j){
                int r = d_[j] / RNODES2;
                r_[j]  = r;
                dl_[j] = d_[j] - r*RNODES2;
                rk_[j] = atomicAdd(&wcnt[w*RGS + r], 1);
            }
        }
        __syncthreads();
        if (tid < RGS){
            int c0 = wcnt[0*RGS+tid], c1 = wcnt[1*RGS+tid];
            int c2 = wcnt[2*RGS+tid], c3 = wcnt[3*RGS+tid];
            int tot = c0+c1+c2+c3;
            int gb = 0;
            if (tot > 0) gb = atomicAdd(&bcur[sg*RGS + tid], tot);
            wb[0*RGS+tid] = gb;
            wb[1*RGS+tid] = gb + c0;
            wb[2*RGS+tid] = gb + c0 + c1;
            wb[3*RGS+tid] = gb + c0 + c1 + c2;
        }
        __syncthreads();
        if (valid){
            #pragma unroll
            for (int j = 0; j < 4; ++j){
                int pos = wb[w*RGS + r_[j]] + rk_[j];
                if (pos < BCAP)
                    bkt[(size_t)(sg*RGS + r_[j])*BCAP + pos] = (dl_[j] << 15) | s_[j];
            }
        }
    }
}

// ---------------- Phase B: per (sg,range): hist -> padded scan -> degree-sort -> CSR segment ----------------

__global__ __launch_bounds__(256) void buildB_kernel(int* __restrict__ bkt,
                                                     const int* __restrict__ bcur,
                                                     int* __restrict__ off2,
                                                     int* __restrict__ deg2,
                                                     int* __restrict__ nid2,
                                                     int* __restrict__ offU){
    __shared__ int hist[RNODES2];      // degree per node
    __shared__ int pref[RNODES2];      // CSR scatter cursor
    __shared__ int seg[BCAP];          // 57.3 KB
    __shared__ int sums[256];
    __shared__ int dh[64];             // degree histogram / sort cursor
    int sg = blockIdx.x / RGS, rg = blockIdx.x % RGS;
    int tid = threadIdx.x;
    int cnt = bcur[sg*RGS + rg];
    if (cnt > BCAP) cnt = BCAP;
    size_t base = (size_t)(sg*RGS + rg)*BCAP;
    int gnode = sg*NN + rg*RNODES2;

    for (int i = tid; i < RNODES2; i += 256) hist[i] = 0;
    if (tid < 64) dh[tid] = 0;
    __syncthreads();
    for (int j = tid; j < cnt; j += 256)
        atomicAdd(&hist[bkt[base + j] >> 15], 1);
    __syncthreads();

    int lo = tid*3, hi = min(lo+3, RNODES2);
    int s = 0;
    for (int i = lo; i < hi; ++i) s += (hist[i] + 3) & ~3;   // padded sizes
    sums[tid] = s; __syncthreads();
    for (int ofs = 1; ofs < 256; ofs <<= 1){
        int v = (tid >= ofs) ? sums[tid-ofs] : 0;
        __syncthreads();
        sums[tid] += v;
        __syncthreads();
    }
    int run = sums[tid] - s;
    for (int i = lo; i < hi; ++i){
        pref[i] = run;                       // CSR cursor (mutated below)
        offU[gnode + i] = (int)base + run;   // unsorted offset (read back in sort)
        run += (hist[i] + 3) & ~3;
    }
    __syncthreads();

    // degree histogram -> prefix -> sorted scatter of (off,deg,nid)
    for (int i = tid; i < RNODES2; i += 256)
        atomicAdd(&dh[min(hist[i], 63)], 1);
    __syncthreads();
    if (tid == 0){
        int r = 0;
        for (int k = 0; k < 64; ++k){ int c = dh[k]; dh[k] = r; r += c; }
    }
    __syncthreads();
    for (int i = tid; i < RNODES2; i += 256){
        int pos = atomicAdd(&dh[min(hist[i], 63)], 1);
        off2[gnode + pos] = offU[gnode + i];
        deg2[gnode + pos] = hist[i];
        nid2[gnode + pos] = rg*RNODES2 + i;
    }
    __syncthreads();

    for (int j = tid; j < cnt; j += 256){
        int p = bkt[base + j];
        int slot = atomicAdd(&pref[p >> 15], 1);
        if (slot < BCAP) seg[slot] = p & 0x7FFF;
    }
    __syncthreads();

    int padtot = min(sums[255], BCAP);
    for (int j = tid; j < padtot; j += 256) bkt[base + j] = seg[j];
}

// ---------------- x -> bf16 convert ----------------

__global__ __launch_bounds__(256) void convert_kernel(const float* __restrict__ x,
                                                      unsigned short* __restrict__ xb){
    int idx = blockIdx.x*256 + threadIdx.x;
    if (idx >= SG*NN*16) return;
    float4 v = ((const float4*)x)[idx];
    uint2 pk;
    pk.x = (unsigned)f2bf(v.x) | ((unsigned)f2bf(v.y) << 16);
    pk.y = (unsigned)f2bf(v.z) | ((unsigned)f2bf(v.w) << 16);
    ((uint2*)xb)[idx] = pk;
}

// ---------------- weight prep: all bf16, [col][k] layouts ----------------

__global__ __launch_bounds__(256) void wprep2_kernel(const float* __restrict__ W1l,
                                                     const float* __restrict__ W1r,
                                                     const float* __restrict__ W2l,
                                                     const float* __restrict__ W2r,
                                                     const float* __restrict__ Wih,
                                                     const float* __restrict__ Whh,
                                                     const float* __restrict__ bih,
                                                     const float* __restrict__ bhh,
                                                     unsigned short* __restrict__ WL1,
                                                     unsigned short* __restrict__ WL2,
                                                     unsigned short* __restrict__ Wt,
                                                     float* __restrict__ bc){
    int idx = blockIdx.x*256 + threadIdx.x;
    if (idx < 24576){
        int g = idx >> 13, rem = idx & 8191, col = rem >> 7, k = rem & 127;
        float v = (k < 64) ? W1l[((size_t)g*64 + k)*64 + col]
                           : W1r[((size_t)g*64 + (k-64))*64 + col];
        WL1[idx] = f2bf(v);
    } else if (idx < 49152){
        int t = idx - 24576;
        int g = t >> 13, rem = t & 8191, col = rem >> 7, k = rem & 127;
        float v = (k < 64) ? W2l[((size_t)g*64 + k)*64 + col]
                           : W2r[((size_t)g*64 + (k-64))*64 + col];
        WL2[t] = f2bf(v);
    } else if (idx < 81920){
        int t = idx - 49152;
        int col = t >> 7, k = t & 127;
        float v = (k < 64) ? Wih[col*64 + k] : Whh[col*64 + (k - 64)];
        Wt[t] = f2bf(v);
    } else if (idx < 82176){
        int t = idx - 81920;
        bc[t] = bih[t] + bhh[t];
    }
}

// ---------------- SAGE layer: identity-B MFMA segment-sum ----------------

#define WP 72

#define LOADC(F, BASE) { \
    int s0_ = (BASE) + (q >> 1); \
    int s1_ = s0_ + 2; \
    int n0_ = csr[a + s0_]; \
    int n1_ = csr[a + s1_]; \
    unsigned o0_ = (s0_ < dg) ? (((unsigned)n0_) << 7) : zoff0; \
    unsigned o1_ = (s1_ < dg) ? (((unsigned)n1_) << 7) : zoff0; \
    o0_ += qh; o1_ += qh; \
    F[0] = *(const bf16x8*)(inbc + o0_); \
    F[1] = *(const bf16x8*)(inbc + o0_ + 32); \
    F[2] = *(const bf16x8*)(inbc + o0_ + 64); \
    F[3] = *(const bf16x8*)(inbc + o0_ + 96); \
    F[4] = *(const bf16x8*)(inbc + o1_); \
    F[5] = *(const bf16x8*)(inbc + o1_ + 32); \
    F[6] = *(const bf16x8*)(inbc + o1_ + 64); \
    F[7] = *(const bf16x8*)(inbc + o1_ + 96); \
}

#define MFMA8(F) { \
    acc[0] = __builtin_amdgcn_mfma_f32_16x16x32_bf16(F[0], BI, acc[0], 0, 0, 0); \
    acc[1] = __builtin_amdgcn_mfma_f32_16x16x32_bf16(F[1], BI, acc[1], 0, 0, 0); \
    acc[2] = __builtin_amdgcn_mfma_f32_16x16x32_bf16(F[2], BI, acc[2], 0, 0, 0); \
    acc[3] = __builtin_amdgcn_mfma_f32_16x16x32_bf16(F[3], BI, acc[3], 0, 0, 0); \
    acc[0] = __builtin_amdgcn_mfma_f32_16x16x32_bf16(F[4], BI, acc[0], 0, 0, 0); \
    acc[1] = __builtin_amdgcn_mfma_f32_16x16x32_bf16(F[5], BI, acc[1], 0, 0, 0); \
    acc[2] = __builtin_amdgcn_mfma_f32_16x16x32_bf16(F[6], BI, acc[2], 0, 0, 0); \
    acc[3] = __builtin_amdgcn_mfma_f32_16x16x32_bf16(F[7], BI, acc[3], 0, 0, 0); \
}

__global__ __launch_bounds__(256,4) void layer_kernel(const unsigned short* __restrict__ xb,
                                                    const int* __restrict__ off2,
                                                    const int* __restrict__ deg2,
                                                    const int* __restrict__ nid2,
                                                    const int* __restrict__ csr,
                                                    const unsigned short* __restrict__ WL,
                                                    const float* __restrict__ bias,
                                                    unsigned short* __restrict__ outb){
    __shared__ unsigned short sM[4][16*WP];
    __shared__ unsigned short sO[4][16*WP];
    int L = blockIdx.x;
    int xcd = L & 7;
    int task = ((xcd < LR) ? xcd*(LQ+1) : LR*(LQ+1) + (xcd-LR)*LQ) + (L >> 3);
    int sg = task / LTILES;
    int tsel = task - sg*LTILES;
    int tile = (LTILES-1) - tsel;           // high-degree (long) blocks first
    int g = sg % G;
    int tid = threadIdx.x;
    int wave = tid >> 6, lane = tid & 63;
    int r = lane & 15, q = lane >> 4;
    unsigned qh = (unsigned)((q & 1) << 4);
    const char* inbc = (const char*)(xb + (size_t)sg*NN*D);

    int gid = tile*4 + wave;
    bool wv = (gid < NGRP);

    // identity-B fragment: B[k][col]=1 iff (k&15)==col  (col=r, k=q*8+j)
    union { uint4 u; bf16x8 v; } biu;
    {
        unsigned v_ = 0x3F80u << ((r & 1) * 16);
        bool on = ((r >> 3) == (q & 1));
        int w_ = (r & 7) >> 1;
        biu.u.x = (on && w_ == 0) ? v_ : 0u;
        biu.u.y = (on && w_ == 1) ? v_ : 0u;
        biu.u.z = (on && w_ == 2) ? v_ : 0u;
        biu.u.w = (on && w_ == 3) ? v_ : 0u;
    }
    bf16x8 BI = biu.v;

    int idx = sg*NN + gid*16 + r;
    int node = 0, dg = 0, a = 0;
    if (wv){
        node = nid2[idx];
        a    = off2[idx];
        dg   = deg2[idx];
    }
    int mx = dg;
    mx = max(mx, __shfl_xor(mx, 1));
    mx = max(mx, __shfl_xor(mx, 2));
    mx = max(mx, __shfl_xor(mx, 4));
    mx = max(mx, __shfl_xor(mx, 8));

    unsigned zoff0 = (((unsigned)((SG - sg)*NN)) << 7);

    f32x4 acc[4];
    #pragma unroll
    for (int cb = 0; cb < 4; ++cb) acc[cb] = (f32x4){0.f,0.f,0.f,0.f};

    if (mx > 0){
        int nch = (mx + 3) >> 2;
        bf16x8 Fa[8], Fb[8];
        LOADC(Fa, 0);
        for (int c = 0; c < nch; c += 2){
            if (c + 1 < nch) LOADC(Fb, (c + 1)*4);
            MFMA8(Fa);
            if (c + 1 < nch){
                if (c + 2 < nch) LOADC(Fa, (c + 2)*4);
                MFMA8(Fb);
            }
        }
    }

    float inv[4];
    #pragma unroll
    for (int reg = 0; reg < 4; ++reg){
        int d = __shfl(dg, (q << 2) | reg, 16);
        inv[reg] = (d > 0) ? rcpf((float)d) : 0.0f;
    }
    #pragma unroll
    for (int cb = 0; cb < 4; ++cb)
        #pragma unroll
        for (int reg = 0; reg < 4; ++reg)
            sM[wave][(q*4 + reg)*WP + cb*16 + r] = f2bf(acc[cb][reg] * inv[reg]);

    // matmul: C = mean@Wl + self@Wr
    const unsigned short* WLg = WL + (size_t)g*64*128;
    f32x4 accv[4];
    #pragma unroll
    for (int ct = 0; ct < 4; ++ct) accv[ct] = (f32x4){0.f,0.f,0.f,0.f};
    #pragma unroll
    for (int kc = 0; kc < 4; ++kc){
        bf16x8 af;
        if (kc < 2) af = *(const bf16x8*)&sM[wave][r*WP + kc*32 + q*8];
        else        af = *(const bf16x8*)(inbc + (((unsigned)node) << 7) + (unsigned)((kc-2)*64 + q*16));
        #pragma unroll
        for (int ct = 0; ct < 4; ++ct){
            bf16x8 bfr = *(const bf16x8*)&WLg[(ct*16 + r)*128 + kc*32 + q*8];
            accv[ct] = __builtin_amdgcn_mfma_f32_16x16x32_bf16(af, bfr, accv[ct], 0, 0, 0);
        }
    }

    #pragma unroll
    for (int ct = 0; ct < 4; ++ct){
        float bv = bias[g*64 + ct*16 + r];
        #pragma unroll
        for (int reg = 0; reg < 4; ++reg)
            sO[wave][(q*4+reg)*WP + ct*16 + r] = f2bf(tanhf_fast(accv[ct][reg] + bv));
    }
    if (wv){
        #pragma unroll
        for (int pass = 0; pass < 2; ++pass){
            int rloc = pass*8 + (lane >> 3), chunk = lane & 7;
            int i2 = gid*16 + rloc;
            int nd = nid2[sg*NN + i2];
            uint4 v = *(const uint4*)&sO[wave][rloc*WP + chunk*8];
            *(uint4*)&outb[((size_t)sg*NN + nd)*D + chunk*8] = v;
        }
    }
}

// ---------------- LSTM: col-partitioned waves; Wt read once per block; 3 barriers ----------------

__global__ __launch_bounds__(256) void lstm_kernel(const unsigned short* __restrict__ h2b,
                                                   const unsigned short* __restrict__ Wt,
                                                   const float* __restrict__ bc,
                                                   float* __restrict__ out){
    __shared__ unsigned short sH[64*WP];  // 9.2 KB, whole block's h
    int tid = threadIdx.x;
    int b0 = blockIdx.x * 64;
    int wave = tid >> 6, lane = tid & 63;
    int n0 = lane & 15, q = lane >> 4;
    int jcol = wave*16 + n0;              // output col j in [0,64)

    float bb[4];
    #pragma unroll
    for (int T = 0; T < 4; ++T) bb[T] = bc[T*64 + jcol];

    float c[4][4];  // [rt][reg]
    #pragma unroll
    for (int rt = 0; rt < 4; ++rt)
        #pragma unroll
        for (int reg = 0; reg < 4; ++reg) c[rt][reg] = 0.0f;

    int s_[4], n_[4];
    #pragma unroll
    for (int rt = 0; rt < 4; ++rt){
        int b = b0 + rt*16 + n0;
        s_[rt] = b / NN; n_[rt] = b - s_[rt]*NN;
    }

    #pragma unroll
    for (int t = 0; t < G; ++t){
        f32x4 accv[4][4];  // [rt][T]
        #pragma unroll
        for (int rt = 0; rt < 4; ++rt)
            #pragma unroll
            for (int T = 0; T < 4; ++T) accv[rt][T] = (f32x4){0.f,0.f,0.f,0.f};

        int nkc = (t == 0) ? 2 : 4;
        #pragma unroll
        for (int kc = 0; kc < 4; ++kc){
            if (kc >= nkc) break;
            bf16x8 af[4];
            #pragma unroll
            for (int rt = 0; rt < 4; ++rt){
                if (kc < 2) af[rt] = *(const bf16x8*)&h2b[((size_t)(s_[rt]*G + t)*NN + n_[rt])*D + kc*32 + q*8];
                else        af[rt] = *(const bf16x8*)&sH[(rt*16 + n0)*WP + (kc-2)*32 + q*8];
            }
            #pragma unroll
            for (int T = 0; T < 4; ++T){
                int ct = T*4 + wave;
                bf16x8 bfr = *(const bf16x8*)&Wt[(ct*16 + n0)*128 + kc*32 + q*8];
                #pragma unroll
                for (int rt = 0; rt < 4; ++rt)
                    accv[rt][T] = __builtin_amdgcn_mfma_f32_16x16x32_bf16(af[rt], bfr, accv[rt][T], 0, 0, 0);
            }
        }
        if (t > 0) __syncthreads();   // WAR: all sH reads done before overwrite

        #pragma unroll
        for (int rt = 0; rt < 4; ++rt){
            #pragma unroll
            for (int reg = 0; reg < 4; ++reg){
                float ig = sigmf(accv[rt][0][reg] + bb[0]);
                float fg = sigmf(accv[rt][1][reg] + bb[1]);
                float gg = tanhf_fast(accv[rt][2][reg] + bb[2]);
                float og = sigmf(accv[rt][3][reg] + bb[3]);
                float cn = fg*c[rt][reg] + ig*gg;
                c[rt][reg] = cn;
                float hv = og * tanhf_fast(cn);
                int row = rt*16 + q*4 + reg;
                if (t < G-1) sH[row*WP + jcol] = f2bf(hv);
                else         out[(size_t)(b0 + row)*D + jcol] = hv;
            }
        }
        if (t < G-1) __syncthreads(); // RAW: h visible before next t's reads
    }
}

// ---------------- host ----------------

extern "C" void kernel_launch(void* const* d_in, const int* in_sizes, int n_in,
                              void* d_out, int out_size, void* d_ws, size_t ws_size,
                              hipStream_t stream) {
    const float* x   = (const float*)d_in[0];
    const int*   ei  = (const int*)  d_in[1];
    const float* W1l = (const float*)d_in[2];
    const float* W1r = (const float*)d_in[3];
    const float* b1  = (const float*)d_in[4];
    const float* W2l = (const float*)d_in[5];
    const float* W2r = (const float*)d_in[6];
    const float* b2  = (const float*)d_in[7];
    const float* Wih = (const float*)d_in[8];
    const float* Whh = (const float*)d_in[9];
    const float* bih = (const float*)d_in[10];
    const float* bhh = (const float*)d_in[11];
    float* out = (float*)d_out;

    char* ws = (char*)d_ws;
    size_t cur = 0;
    auto alloc = [&](size_t bytes)->void*{
        cur = (cur + 255) & ~(size_t)255;
        void* p = ws + cur; cur += bytes; return p;
    };
    int*   bkt  = (int*)alloc((size_t)SG*RGS*BCAP*4);   // buckets, then CSR in place
    int*   bcur = (int*)alloc((size_t)SG*RGS*4);
    int*   off2 = (int*)alloc((size_t)SG*NN*4);
    int*   deg2 = (int*)alloc((size_t)SG*NN*4);
    int*   nid2 = (int*)alloc((size_t)SG*NN*4);
    int*   offU = (int*)alloc((size_t)SG*NN*4);
    unsigned short* xb  = (unsigned short*)alloc(((size_t)SG*NN + 1)*D*2);  // +1 zero row
    unsigned short* h1b = (unsigned short*)alloc(((size_t)SG*NN + 1)*D*2);  // +1 zero row
    unsigned short* h2b = (unsigned short*)alloc((size_t)SG*NN*D*2);
    unsigned short* WL1 = (unsigned short*)alloc((size_t)G*64*128*2);
    unsigned short* WL2 = (unsigned short*)alloc((size_t)G*64*128*2);
    unsigned short* Wt  = (unsigned short*)alloc((size_t)256*128*2);
    float* bc   = (float*)alloc((size_t)256*4);
    (void)ws_size; (void)in_sizes; (void)n_in; (void)out_size;

    (void)hipMemsetAsync(bcur, 0, (size_t)SG*RGS*4, stream);
    (void)hipMemsetAsync(xb  + (size_t)SG*NN*D, 0, (size_t)D*2, stream);  // shared zero row
    (void)hipMemsetAsync(h1b + (size_t)SG*NN*D, 0, (size_t)D*2, stream);  // shared zero row

    convert_kernel<<<(SG*NN*16 + 255)/256, 256, 0, stream>>>(x, xb);
    binA_kernel  <<<dim3(CHUNKA, SG), 256, 0, stream>>>(ei, bcur, bkt);
    buildB_kernel<<<SG*RGS, 256, 0, stream>>>(bkt, bcur, off2, deg2, nid2, offU);
    wprep2_kernel<<<321, 256, 0, stream>>>(W1l, W1r, W2l, W2r, Wih, Whh, bih, bhh,
                                           WL1, WL2, Wt, bc);

    layer_kernel<<<LTASKS, 256, 0, stream>>>(xb,  off2, deg2, nid2, bkt, WL1, b1, h1b);
    layer_kernel<<<LTASKS, 256, 0, stream>>>(h1b, off2, deg2, nid2, bkt, WL2, b2, h2b);

    lstm_kernel <<<(S*NN)/64, 256, 0, stream>>>(h2b, Wt, bc, out);
}

// Round 6
// 382.274 us; speedup vs baseline: 1.2097x; 1.1788x over previous
//
#include <hip/hip_runtime.h>
#include <math.h>

#define S 4
#define G 3
#define NN 20000
#define EE 320000
#define D 64
#define SG (S*G)

#define RGS 32           // dst-ranges per graph
#define RNODES2 625      // NN / RGS
#define BCAP 14336       // bucket capacity per (sg,range); mean 10000 + pad(<=3/node)
#define CHUNKA 100       // edge chunks per sg in binA; 320000/100 = 3200 edges/block

// layer tasks: 12 sg x 313 tiles (block = 64 consecutive sorted ranks, 4 waves x 16)
#define LTILES 313
#define LTASKS (12*LTILES)   // 3756
#define LQ (LTASKS/8)        // 469
#define LR (LTASKS%8)        // 4
#define NGRP   (NN/16)       // 1250 sorted 16-row groups per sg

static __device__ __forceinline__ float rcpf(float x){ return __builtin_amdgcn_rcpf(x); }
static __device__ __forceinline__ float sigmf(float x){ return rcpf(1.0f + __expf(-x)); }
static __device__ __forceinline__ float tanhf_fast(float x){
    float t = __expf(2.0f*x);
    return 1.0f - 2.0f*rcpf(t + 1.0f);
}

// float -> bf16 bits, round-nearest-even
static __device__ __forceinline__ unsigned short f2bf(float f){
    union { float f; unsigned u; } v; v.f = f;
    unsigned r = v.u + 0x7FFF + ((v.u >> 16) & 1);
    return (unsigned short)(r >> 16);
}

typedef short bf16x8 __attribute__((ext_vector_type(8)));
typedef float f32x4  __attribute__((ext_vector_type(4)));

// ---------------- Phase A: bin edges into 32 dst-range buckets, packed (dstLoc<<15)|src ----------------

__global__ __launch_bounds__(256) void binA_kernel(const int* __restrict__ ei,
                                                   int* __restrict__ bcur,
                                                   int* __restrict__ bkt){
    __shared__ int wcnt[4*RGS];
    __shared__ int wb[4*RGS];
    int chunk = blockIdx.x, sg = blockIdx.y;
    int tid = threadIdx.x, w = tid >> 6;
    const int* srcp = ei + (size_t)(sg*2 + 0)*EE;
    const int* dstp = ei + (size_t)(sg*2 + 1)*EE;
    const int EPC = EE/CHUNKA;               // 3200
    int start = chunk*EPC, end = start + EPC;

    for (int it = 0; it < (EPC + 1023)/1024; ++it){
        if (tid < 4*RGS) wcnt[tid] = 0;
        __syncthreads();
        int e = start + it*1024 + tid*4;
        bool valid = e < end;
        int d_[4], s_[4], r_[4], dl_[4], rk_[4];
        if (valid){
            int4 d4 = *(const int4*)&dstp[e];
            int4 s4 = *(const int4*)&srcp[e];
            d_[0]=d4.x; d_[1]=d4.y; d_[2]=d4.z; d_[3]=d4.w;
            s_[0]=s4.x; s_[1]=s4.y; s_[2]=s4.z; s_[3]=s4.w;
            #pragma unroll
            for (int j = 0; j < 4; ++j){
                int r = d_[j] / RNODES2;
                r_[j]  = r;
                dl_[j] = d_[j] - r*RNODES2;
                rk_[j] = atomicAdd(&wcnt[w*RGS + r], 1);
            }
        }
        __syncthreads();
        if (tid < RGS){
            int c0 = wcnt[0*RGS+tid], c1 = wcnt[1*RGS+tid];
            int c2 = wcnt[2*RGS+tid], c3 = wcnt[3*RGS+tid];
            int tot = c0+c1+c2+c3;
            int gb = 0;
            if (tot > 0) gb = atomicAdd(&bcur[sg*RGS + tid], tot);
            wb[0*RGS+tid] = gb;
            wb[1*RGS+tid] = gb + c0;
            wb[2*RGS+tid] = gb + c0 + c1;
            wb[3*RGS+tid] = gb + c0 + c1 + c2;
        }
        __syncthreads();
        if (valid){
            #pragma unroll
            for (int j = 0; j < 4; ++j){
                int pos = wb[w*RGS + r_[j]] + rk_[j];
                if (pos < BCAP)
                    bkt[(size_t)(sg*RGS + r_[j])*BCAP + pos] = (dl_[j] << 15) | s_[j];
            }
        }
    }
}

// ---------------- Phase B: per (sg,range): hist -> padded scan -> degree-sort -> CSR segment ----------------

__global__ __launch_bounds__(256) void buildB_kernel(int* __restrict__ bkt,
                                                     const int* __restrict__ bcur,
                                                     int* __restrict__ off2,
                                                     int* __restrict__ deg2,
                                                     int* __restrict__ nid2,
                                                     int* __restrict__ offU){
    __shared__ int hist[RNODES2];      // degree per node
    __shared__ int pref[RNODES2];      // CSR scatter cursor
    __shared__ int seg[BCAP];          // 57.3 KB
    __shared__ int sums[256];
    __shared__ int dh[64];             // degree histogram / sort cursor
    int sg = blockIdx.x / RGS, rg = blockIdx.x % RGS;
    int tid = threadIdx.x;
    int cnt = bcur[sg*RGS + rg];
    if (cnt > BCAP) cnt = BCAP;
    size_t base = (size_t)(sg*RGS + rg)*BCAP;
    int gnode = sg*NN + rg*RNODES2;

    for (int i = tid; i < RNODES2; i += 256) hist[i] = 0;
    if (tid < 64) dh[tid] = 0;
    __syncthreads();
    for (int j = tid; j < cnt; j += 256)
        atomicAdd(&hist[bkt[base + j] >> 15], 1);
    __syncthreads();

    int lo = tid*3, hi = min(lo+3, RNODES2);
    int s = 0;
    for (int i = lo; i < hi; ++i) s += (hist[i] + 3) & ~3;   // padded sizes
    sums[tid] = s; __syncthreads();
    for (int ofs = 1; ofs < 256; ofs <<= 1){
        int v = (tid >= ofs) ? sums[tid-ofs] : 0;
        __syncthreads();
        sums[tid] += v;
        __syncthreads();
    }
    int run = sums[tid] - s;
    for (int i = lo; i < hi; ++i){
        pref[i] = run;                       // CSR cursor (mutated below)
        offU[gnode + i] = (int)base + run;   // unsorted offset (read back in sort)
        run += (hist[i] + 3) & ~3;
    }
    __syncthreads();

    // degree histogram -> prefix -> sorted scatter of (off,deg,nid)
    for (int i = tid; i < RNODES2; i += 256)
        atomicAdd(&dh[min(hist[i], 63)], 1);
    __syncthreads();
    if (tid == 0){
        int r = 0;
        for (int k = 0; k < 64; ++k){ int c = dh[k]; dh[k] = r; r += c; }
    }
    __syncthreads();
    for (int i = tid; i < RNODES2; i += 256){
        int pos = atomicAdd(&dh[min(hist[i], 63)], 1);
        off2[gnode + pos] = offU[gnode + i];
        deg2[gnode + pos] = hist[i];
        nid2[gnode + pos] = rg*RNODES2 + i;
    }
    __syncthreads();

    for (int j = tid; j < cnt; j += 256){
        int p = bkt[base + j];
        int slot = atomicAdd(&pref[p >> 15], 1);
        if (slot < BCAP) seg[slot] = p & 0x7FFF;
    }
    __syncthreads();

    int padtot = min(sums[255], BCAP);
    for (int j = tid; j < padtot; j += 256) bkt[base + j] = seg[j];
}

// ---------------- x -> bf16 convert ----------------

__global__ __launch_bounds__(256) void convert_kernel(const float* __restrict__ x,
                                                      unsigned short* __restrict__ xb){
    int idx = blockIdx.x*256 + threadIdx.x;
    if (idx >= SG*NN*16) return;
    float4 v = ((const float4*)x)[idx];
    uint2 pk;
    pk.x = (unsigned)f2bf(v.x) | ((unsigned)f2bf(v.y) << 16);
    pk.y = (unsigned)f2bf(v.z) | ((unsigned)f2bf(v.w) << 16);
    ((uint2*)xb)[idx] = pk;
}

// ---------------- weight prep: all bf16, [col][k] layouts ----------------

__global__ __launch_bounds__(256) void wprep2_kernel(const float* __restrict__ W1l,
                                                     const float* __restrict__ W1r,
                                                     const float* __restrict__ W2l,
                                                     const float* __restrict__ W2r,
                                                     const float* __restrict__ Wih,
                                                     const float* __restrict__ Whh,
                                                     const float* __restrict__ bih,
                                                     const float* __restrict__ bhh,
                                                     unsigned short* __restrict__ WL1,
                                                     unsigned short* __restrict__ WL2,
                                                     unsigned short* __restrict__ Wt,
                                                     float* __restrict__ bc){
    int idx = blockIdx.x*256 + threadIdx.x;
    if (idx < 24576){
        int g = idx >> 13, rem = idx & 8191, col = rem >> 7, k = rem & 127;
        float v = (k < 64) ? W1l[((size_t)g*64 + k)*64 + col]
                           : W1r[((size_t)g*64 + (k-64))*64 + col];
        WL1[idx] = f2bf(v);
    } else if (idx < 49152){
        int t = idx - 24576;
        int g = t >> 13, rem = t & 8191, col = rem >> 7, k = rem & 127;
        float v = (k < 64) ? W2l[((size_t)g*64 + k)*64 + col]
                           : W2r[((size_t)g*64 + (k-64))*64 + col];
        WL2[t] = f2bf(v);
    } else if (idx < 81920){
        int t = idx - 49152;
        int col = t >> 7, k = t & 127;
        float v = (k < 64) ? Wih[col*64 + k] : Whh[col*64 + (k - 64)];
        Wt[t] = f2bf(v);
    } else if (idx < 82176){
        int t = idx - 81920;
        bc[t] = bih[t] + bhh[t];
    }
}

// ---------------- SAGE layer: identity-B MFMA segment-sum with LDS-staged gather.
// Gather: round-0's coalesced pattern (8 lanes x 16B = one 128B line per edge) into
// a per-wave 8KB stage buffer (XOR-swizzled granules); ds_read_b128 the MFMA
// A-fragments out of LDS. Decouples coalescing from fragment layout. ----------------

#define WP 72
#define SWZ(e) ((((e) >> 1) ^ ((e) >> 4)) & 7)

__global__ __launch_bounds__(256,4) void layer_kernel(const unsigned short* __restrict__ xb,
                                                    const int* __restrict__ off2,
                                                    const int* __restrict__ deg2,
                                                    const int* __restrict__ nid2,
                                                    const int* __restrict__ csr,
                                                    const unsigned short* __restrict__ WL,
                                                    const float* __restrict__ bias,
                                                    unsigned short* __restrict__ outb){
    // 8KB per wave: 64 edges x 128B, swizzled. After the loop, shorts [0,1152) are
    // reused as the mean tile (sM) and [2048,3200) as the out tile (sO) - same wave,
    // LDS ops in program order, no barrier needed.
    __shared__ unsigned short sStage[4][4096];
    int L = blockIdx.x;
    int xcd = L & 7;
    int task = ((xcd < LR) ? xcd*(LQ+1) : LR*(LQ+1) + (xcd-LR)*LQ) + (L >> 3);
    int sg = task / LTILES;
    int tsel = task - sg*LTILES;
    int tile = (LTILES-1) - tsel;           // high-degree (long) blocks first
    int g = sg % G;
    int tid = threadIdx.x;
    int wave = tid >> 6, lane = tid & 63;
    int r = lane & 15, q = lane >> 4;
    const char* inbc = (const char*)(xb + (size_t)sg*NN*D);
    unsigned short* stg = &sStage[wave][0];

    int gid = tile*4 + wave;
    bool wv = (gid < NGRP);

    // identity-B fragment: B[k][col]=1 iff (k&15)==col (round-5 hardware-verified)
    union { uint4 u; bf16x8 v; } biu;
    {
        unsigned v_ = 0x3F80u << ((r & 1) * 16);
        bool on = ((r >> 3) == (q & 1));
        int w_ = (r & 7) >> 1;
        biu.u.x = (on && w_ == 0) ? v_ : 0u;
        biu.u.y = (on && w_ == 1) ? v_ : 0u;
        biu.u.z = (on && w_ == 2) ? v_ : 0u;
        biu.u.w = (on && w_ == 3) ? v_ : 0u;
    }
    bf16x8 BI = biu.v;

    int idx = sg*NN + gid*16 + r;
    int node = 0, dg = 0, a = 0;
    if (wv){
        node = nid2[idx];
        a    = off2[idx];
        dg   = deg2[idx];
    }
    int mx = dg;
    mx = max(mx, __shfl_xor(mx, 1));
    mx = max(mx, __shfl_xor(mx, 2));
    mx = max(mx, __shfl_xor(mx, 4));
    mx = max(mx, __shfl_xor(mx, 8));

    unsigned zoff0 = (((unsigned)((SG - sg)*NN)) << 7);

    // gather-role: lane handles edge (row lane>>2, slot lane&3) of each chunk
    int aG  = __shfl(a,  lane >> 2);
    int dgG = __shfl(dg, lane >> 2);

    f32x4 acc[4];
    #pragma unroll
    for (int cb = 0; cb < 4; ++cb) acc[cb] = (f32x4){0.f,0.f,0.f,0.f};

    int nch = (mx + 3) >> 2;
    for (int c = 0; c < nch; ++c){
        // A. per-lane edge address (slot validity -> shared zero row)
        int sL = c*4 + (lane & 3);
        int nL = csr[aG + sL];               // padded CSR: in-bounds read, value masked below
        unsigned adr = (sL < dgG) ? (((unsigned)nL) << 7) : zoff0;
        // B. coalesced gathers: inst j reads 8 rows, 8 consecutive lanes x 16B per row
        uint4 v[8];
        #pragma unroll
        for (int j = 0; j < 8; ++j){
            unsigned ae = (unsigned)__shfl((int)adr, j*8 + (lane >> 3));
            v[j] = *(const uint4*)(inbc + ae + (unsigned)((lane & 7) << 4));
        }
        // C. stage to LDS, granule-swizzled (write side of SWZ)
        #pragma unroll
        for (int j = 0; j < 8; ++j){
            int e = j*8 + (lane >> 3);
            int gr = ((lane & 7) ^ SWZ(e)) << 4;
            *(uint4*)((char*)stg + e*128 + gr) = v[j];
        }
        // D. identity-B MFMA fragments from LDS (read side of SWZ)
        #pragma unroll
        for (int m = 0; m < 2; ++m){
            int e = r*4 + m*2 + (q >> 1);
            int ebase = e*128;
            int sw = SWZ(e) << 4;
            #pragma unroll
            for (int cb = 0; cb < 4; ++cb){
                int b = cb*32 + ((q & 1) << 4);
                bf16x8 af = *(const bf16x8*)((const char*)stg + ebase + (b ^ sw));
                acc[cb] = __builtin_amdgcn_mfma_f32_16x16x32_bf16(af, BI, acc[cb], 0, 0, 0);
            }
        }
    }

    // mean: scale by 1/deg of row (q*4+reg); write bf16 mean into sM overlay
    asm volatile("" ::: "memory");
    unsigned short* sMw = stg;               // shorts [0, 1152)
    float inv[4];
    #pragma unroll
    for (int reg = 0; reg < 4; ++reg){
        int d = __shfl(dg, (q << 2) | reg, 16);
        inv[reg] = (d > 0) ? rcpf((float)d) : 0.0f;
    }
    #pragma unroll
    for (int cb = 0; cb < 4; ++cb)
        #pragma unroll
        for (int reg = 0; reg < 4; ++reg)
            sMw[(q*4 + reg)*WP + cb*16 + r] = f2bf(acc[cb][reg] * inv[reg]);
    asm volatile("" ::: "memory");

    // matmul: C = mean@Wl + self@Wr
    const unsigned short* WLg = WL + (size_t)g*64*128;
    f32x4 accv[4];
    #pragma unroll
    for (int ct = 0; ct < 4; ++ct) accv[ct] = (f32x4){0.f,0.f,0.f,0.f};
    #pragma unroll
    for (int kc = 0; kc < 4; ++kc){
        bf16x8 af;
        if (kc < 2) af = *(const bf16x8*)&sMw[r*WP + kc*32 + q*8];
        else        af = *(const bf16x8*)(inbc + (((unsigned)node) << 7) + (unsigned)((kc-2)*64 + q*16));
        #pragma unroll
        for (int ct = 0; ct < 4; ++ct){
            bf16x8 bfr = *(const bf16x8*)&WLg[(ct*16 + r)*128 + kc*32 + q*8];
            accv[ct] = __builtin_amdgcn_mfma_f32_16x16x32_bf16(af, bfr, accv[ct], 0, 0, 0);
        }
    }

    // epilogue: bias + tanh -> bf16, transpose through sO overlay, scatter by nid
    asm volatile("" ::: "memory");
    unsigned short* sOw = stg + 2048;        // shorts [2048, 3200)
    #pragma unroll
    for (int ct = 0; ct < 4; ++ct){
        float bv = bias[g*64 + ct*16 + r];
        #pragma unroll
        for (int reg = 0; reg < 4; ++reg)
            sOw[(q*4+reg)*WP + ct*16 + r] = f2bf(tanhf_fast(accv[ct][reg] + bv));
    }
    asm volatile("" ::: "memory");
    if (wv){
        #pragma unroll
        for (int pass = 0; pass < 2; ++pass){
            int rloc = pass*8 + (lane >> 3), chunk = lane & 7;
            int i2 = gid*16 + rloc;
            int nd = nid2[sg*NN + i2];
            uint4 v = *(const uint4*)&sOw[rloc*WP + chunk*8];
            *(uint4*)&outb[((size_t)sg*NN + nd)*D + chunk*8] = v;
        }
    }
}

// ---------------- LSTM: col-partitioned waves; Wt read once per block; 3 barriers ----------------

__global__ __launch_bounds__(256) void lstm_kernel(const unsigned short* __restrict__ h2b,
                                                   const unsigned short* __restrict__ Wt,
                                                   const float* __restrict__ bc,
                                                   float* __restrict__ out){
    __shared__ unsigned short sH[64*WP];  // 9.2 KB, whole block's h
    int tid = threadIdx.x;
    int b0 = blockIdx.x * 64;
    int wave = tid >> 6, lane = tid & 63;
    int n0 = lane & 15, q = lane >> 4;
    int jcol = wave*16 + n0;              // output col j in [0,64)

    float bb[4];
    #pragma unroll
    for (int T = 0; T < 4; ++T) bb[T] = bc[T*64 + jcol];

    float c[4][4];  // [rt][reg]
    #pragma unroll
    for (int rt = 0; rt < 4; ++rt)
        #pragma unroll
        for (int reg = 0; reg < 4; ++reg) c[rt][reg] = 0.0f;

    int s_[4], n_[4];
    #pragma unroll
    for (int rt = 0; rt < 4; ++rt){
        int b = b0 + rt*16 + n0;
        s_[rt] = b / NN; n_[rt] = b - s_[rt]*NN;
    }

    #pragma unroll
    for (int t = 0; t < G; ++t){
        f32x4 accv[4][4];  // [rt][T]
        #pragma unroll
        for (int rt = 0; rt < 4; ++rt)
            #pragma unroll
            for (int T = 0; T < 4; ++T) accv[rt][T] = (f32x4){0.f,0.f,0.f,0.f};

        int nkc = (t == 0) ? 2 : 4;
        #pragma unroll
        for (int kc = 0; kc < 4; ++kc){
            if (kc >= nkc) break;
            bf16x8 af[4];
            #pragma unroll
            for (int rt = 0; rt < 4; ++rt){
                if (kc < 2) af[rt] = *(const bf16x8*)&h2b[((size_t)(s_[rt]*G + t)*NN + n_[rt])*D + kc*32 + q*8];
                else        af[rt] = *(const bf16x8*)&sH[(rt*16 + n0)*WP + (kc-2)*32 + q*8];
            }
            #pragma unroll
            for (int T = 0; T < 4; ++T){
                int ct = T*4 + wave;
                bf16x8 bfr = *(const bf16x8*)&Wt[(ct*16 + n0)*128 + kc*32 + q*8];
                #pragma unroll
                for (int rt = 0; rt < 4; ++rt)
                    accv[rt][T] = __builtin_amdgcn_mfma_f32_16x16x32_bf16(af[rt], bfr, accv[rt][T], 0, 0, 0);
            }
        }
        if (t > 0) __syncthreads();   // WAR: all sH reads done before overwrite

        #pragma unroll
        for (int rt = 0; rt < 4; ++rt){
            #pragma unroll
            for (int reg = 0; reg < 4; ++reg){
                float ig = sigmf(accv[rt][0][reg] + bb[0]);
                float fg = sigmf(accv[rt][1][reg] + bb[1]);
                float gg = tanhf_fast(accv[rt][2][reg] + bb[2]);
                float og = sigmf(accv[rt][3][reg] + bb[3]);
                float cn = fg*c[rt][reg] + ig*gg;
                c[rt][reg] = cn;
                float hv = og * tanhf_fast(cn);
                int row = rt*16 + q*4 + reg;
                if (t < G-1) sH[row*WP + jcol] = f2bf(hv);
                else         out[(size_t)(b0 + row)*D + jcol] = hv;
            }
        }
        if (t < G-1) __syncthreads(); // RAW: h visible before next t's reads
    }
}

// ---------------- host ----------------

extern "C" void kernel_launch(void* const* d_in, const int* in_sizes, int n_in,
                              void* d_out, int out_size, void* d_ws, size_t ws_size,
                              hipStream_t stream) {
    const float* x   = (const float*)d_in[0];
    const int*   ei  = (const int*)  d_in[1];
    const float* W1l = (const float*)d_in[2];
    const float* W1r = (const float*)d_in[3];
    const float* b1  = (const float*)d_in[4];
    const float* W2l = (const float*)d_in[5];
    const float* W2r = (const float*)d_in[6];
    const float* b2  = (const float*)d_in[7];
    const float* Wih = (const float*)d_in[8];
    const float* Whh = (const float*)d_in[9];
    const float* bih = (const float*)d_in[10];
    const float* bhh = (const float*)d_in[11];
    float* out = (float*)d_out;

    char* ws = (char*)d_ws;
    size_t cur = 0;
    auto alloc = [&](size_t bytes)->void*{
        cur = (cur + 255) & ~(size_t)255;
        void* p = ws + cur; cur += bytes; return p;
    };
    int*   bkt  = (int*)alloc((size_t)SG*RGS*BCAP*4);   // buckets, then CSR in place
    int*   bcur = (int*)alloc((size_t)SG*RGS*4);
    int*   off2 = (int*)alloc((size_t)SG*NN*4);
    int*   deg2 = (int*)alloc((size_t)SG*NN*4);
    int*   nid2 = (int*)alloc((size_t)SG*NN*4);
    int*   offU = (int*)alloc((size_t)SG*NN*4);
    unsigned short* xb  = (unsigned short*)alloc(((size_t)SG*NN + 1)*D*2);  // +1 zero row
    unsigned short* h1b = (unsigned short*)alloc(((size_t)SG*NN + 1)*D*2);  // +1 zero row
    unsigned short* h2b = (unsigned short*)alloc((size_t)SG*NN*D*2);
    unsigned short* WL1 = (unsigned short*)alloc((size_t)G*64*128*2);
    unsigned short* WL2 = (unsigned short*)alloc((size_t)G*64*128*2);
    unsigned short* Wt  = (unsigned short*)alloc((size_t)256*128*2);
    float* bc   = (float*)alloc((size_t)256*4);
    (void)ws_size; (void)in_sizes; (void)n_in; (void)out_size;

    (void)hipMemsetAsync(bcur, 0, (size_t)SG*RGS*4, stream);
    (void)hipMemsetAsync(xb  + (size_t)SG*NN*D, 0, (size_t)D*2, stream);  // shared zero row
    (void)hipMemsetAsync(h1b + (size_t)SG*NN*D, 0, (size_t)D*2, stream);  // shared zero row

    convert_kernel<<<(SG*NN*16 + 255)/256, 256, 0, stream>>>(x, xb);
    binA_kernel  <<<dim3(CHUNKA, SG), 256, 0, stream>>>(ei, bcur, bkt);
    buildB_kernel<<<SG*RGS, 256, 0, stream>>>(bkt, bcur, off2, deg2, nid2, offU);
    wprep2_kernel<<<321, 256, 0, stream>>>(W1l, W1r, W2l, W2r, Wih, Whh, bih, bhh,
                                           WL1, WL2, Wt, bc);

    layer_kernel<<<LTASKS, 256, 0, stream>>>(xb,  off2, deg2, nid2, bkt, WL1, b1, h1b);
    layer_kernel<<<LTASKS, 256, 0, stream>>>(h1b, off2, deg2, nid2, bkt, WL2, b2, h2b);

    lstm_kernel <<<(S*NN)/64, 256, 0, stream>>>(h2b, Wt, bc, out);
}